// Round 8
// baseline (64.142 us; speedup 1.0000x reference)
//
#include <hip/hip_runtime.h>
#include <hip/hip_bf16.h>
#include <math.h>

#define BATCH 4096
#define FEAT 128
#define C_TOTAL 16384
#define OUT_TYPES 512

typedef short bf16x8 __attribute__((ext_vector_type(8)));
typedef float f32x4 __attribute__((ext_vector_type(4)));
typedef unsigned short u16;

typedef const __attribute__((address_space(1))) void cg_void;
typedef __attribute__((address_space(3))) void lds_void_t;

static __device__ __forceinline__ u16 f2bf(float f) {
    __hip_bfloat16 h = __float2bfloat16(f);
    return reinterpret_cast<u16&>(h);
}

// ---------------- prologue: out=bias bcast | centres prep | x prep -----------
__global__ void prologue_kernel(const float* __restrict__ x, const float* __restrict__ centres,
                                const float* __restrict__ ls, const float* __restrict__ bias,
                                u16* __restrict__ xb, u16* __restrict__ cbb,
                                float* __restrict__ cc, float* __restrict__ scale,
                                float* __restrict__ hc, float* __restrict__ xx,
                                float* __restrict__ out) {
    const int b = blockIdx.x;
    const int t = threadIdx.x;
    if (b < 2048) {                       // out[m][n] = bias[n], 8 MB
        int i = b * 256 + t;              // float4 index
        float4 bv = reinterpret_cast<const float4*>(bias)[i & 127];
        reinterpret_cast<float4*>(out)[i] = bv;
        return;
    }
    const bool is_c = (b < 2048 + 256);
    const int row = (is_c ? (b - 2048) : (b - 2304)) * 64 + (t >> 2);
    const int l4 = t & 3;
    const float* src = is_c ? centres : x;
    u16* dstb = is_c ? cbb : xb;
    const float4* p = reinterpret_cast<const float4*>(src + (size_t)row * FEAT);
    ushort4* q = reinterpret_cast<ushort4*>(dstb + (size_t)row * FEAT);
    float s = 0.f;
#pragma unroll
    for (int i = 0; i < 8; ++i) {
        float4 v = p[i * 4 + l4];
        s += v.x * v.x + v.y * v.y + v.z * v.z + v.w * v.w;
        ushort4 h;
        h.x = f2bf(v.x); h.y = f2bf(v.y); h.z = f2bf(v.z); h.w = f2bf(v.w);
        q[i * 4 + l4] = h;
    }
    s += __shfl_xor(s, 1);
    s += __shfl_xor(s, 2);
    if (l4 == 0) {
        if (is_c) {
            cc[row] = s;
            scale[row] = __expf(2.f * ls[row]);
            // exact fire condition: sqd*scale < 96 <=> d - 0.5*xx > 0.5*cc - 48/scale
            hc[row] = 0.5f * s - 48.f * __expf(-2.f * ls[row]);
        } else {
            xx[row] = s;
        }
    }
}

// ---------------- rbf: A-in-regs MFMA, 4-buffer counted-vmcnt pipeline -------
// 256 thr / 4 waves, 2 blocks/CU. Wave-tile 128 rows x 16 cols; 128x64/iter.
// A (128x128 bf16) in 128 VGPRs; B staged to LDS (4 x 16 KB) via
// global_load_lds w=16 (pre-swizzled source), STAGE(it+2) issued BEFORE
// s_waitcnt vmcnt(8) -> 2-iter load lead, never drained below 8 mid-loop.
// Loop body: zero global loads, zero register-array runtime indexing.
// Screen: acc init = -0.5*min(xx) of lane's rows; per-iter one 32-max tree vs
// per-lane hmin. Rare hits -> cold post-loop exact recheck + rank-1 update.
#define BM 128
#define BN 64
#define CSPLIT 16
#define CCHUNK (C_TOTAL / CSPLIT) /* 1024 */
#define NIT (CCHUNK / BN)         /* 16 */

__global__ __launch_bounds__(256, 2)
void rbf_kernel(const u16* __restrict__ xb, const u16* __restrict__ cb,
                const float* __restrict__ hc, const float* __restrict__ cc,
                const float* __restrict__ scale, const int* __restrict__ node_id,
                const float* __restrict__ xx, const float* __restrict__ W,
                float* __restrict__ out) {
    __shared__ u16 cs[4][BN * FEAT];      // 4 x 16 KB, granule-swizzled

    const int t = threadIdx.x;
    const int lane = t & 63;
    const int w = t >> 6;                 // col-group 0..3
    const int q = lane >> 4;              // 0..3
    const int r = lane & 15;
    // bijective XCD remap (512 = 8 XCD x 64): each XCD covers 2 centre-chunks
    const int bid = blockIdx.x;
    const int nid = (bid & 7) * 64 + (bid >> 3);
    const int row0 = (nid & 31) * BM;
    const int cbase = (nid >> 5) * CCHUNK;
    const int rB = w * 16 + r;            // centre row within tile (lane's col)
    const int swz = rB & 7;

    // ---- setup: all global metadata consumed before staging ----
    bf16x8 af[8][4];
#pragma unroll
    for (int m = 0; m < 8; ++m) {
        const u16* xrow = xb + (size_t)(row0 + m * 16 + r) * FEAT + q * 8;
#pragma unroll
        for (int ks = 0; ks < 4; ++ks)
            af[m][ks] = *reinterpret_cast<const bf16x8*>(xrow + ks * 32);
    }
    // single acc-bias: -0.5 * min(xx) over the 32 rows this lane owns
    float xmin = 1e30f;
#pragma unroll
    for (int m = 0; m < 8; ++m) {
        float4 v = *reinterpret_cast<const float4*>(&xx[row0 + m * 16 + q * 4]);
        xmin = fminf(xmin, fminf(fminf(v.x, v.y), fminf(v.z, v.w)));
    }
    const float nxh = -0.5f * xmin;
    // single per-lane threshold: min over this lane's 16 per-iter centres
    float hmin = 1e30f;
#pragma unroll
    for (int it = 0; it < NIT; ++it)
        hmin = fminf(hmin, hc[cbase + it * BN + rB]);

    // ---- staging macro (linear LDS dest, swizzled global source) ----
#define STAGE(IT, BUF)                                                         \
    {                                                                          \
        _Pragma("unroll")                                                      \
        for (int p = 0; p < 4; ++p) {                                          \
            int G = t + p * 256;                                               \
            int rr = G >> 4;                                                   \
            int gsrc = (G & 15) ^ (rr & 7);                                    \
            __builtin_amdgcn_global_load_lds(                                  \
                (cg_void*)(cb + (size_t)(cbase + (IT) * BN + rr) * FEAT + gsrc * 8), \
                (lds_void_t*)((char*)cs[BUF] + G * 16), 16, 0, 0);             \
        }                                                                      \
    }
    STAGE(0, 0)
    STAGE(1, 1)

    unsigned sus = 0;
#pragma unroll
    for (int it = 0; it < NIT; ++it) {
        if (it + 2 < NIT) STAGE(it + 2, (it + 2) & 3)   // buf reader done 2 bars ago
        // wait for tile it only (tiles it+1, it+2 = 8 loads stay in flight)
        if (it + 2 < NIT)      asm volatile("s_waitcnt vmcnt(8)" ::: "memory");
        else if (it + 1 < NIT) asm volatile("s_waitcnt vmcnt(4)" ::: "memory");
        else                   asm volatile("s_waitcnt vmcnt(0)" ::: "memory");
        __builtin_amdgcn_s_barrier();     // all waves' tile-it loads landed
        __builtin_amdgcn_sched_barrier(0);

        const u16* brow = cs[it & 3] + rB * FEAT;
        f32x4 acc[8];
#pragma unroll
        for (int m = 0; m < 8; ++m)
            acc[m] = f32x4{nxh, nxh, nxh, nxh};
        __builtin_amdgcn_s_setprio(1);
#pragma unroll
        for (int ks = 0; ks < 4; ++ks) {
            int gk = (ks * 4 + q) ^ swz;
            bf16x8 bf = *reinterpret_cast<const bf16x8*>(brow + gk * 8);
#pragma unroll
            for (int m = 0; m < 8; ++m)
                acc[m] = __builtin_amdgcn_mfma_f32_16x16x32_bf16(af[m][ks], bf, acc[m], 0, 0, 0);
        }
        __builtin_amdgcn_s_setprio(0);

        // screen: one 32-wide max tree vs per-lane hmin
        float pm[8];
#pragma unroll
        for (int m = 0; m < 8; ++m)
            pm[m] = fmaxf(fmaxf(acc[m][0], acc[m][1]), fmaxf(acc[m][2], acc[m][3]));
        float v0 = fmaxf(fmaxf(pm[0], pm[1]), fmaxf(pm[2], pm[3]));
        float v1 = fmaxf(fmaxf(pm[4], pm[5]), fmaxf(pm[6], pm[7]));
        sus |= (fmaxf(v0, v1) > hmin) ? 1u : 0u;
    }
#undef STAGE

    // ---- cold exact path (never taken on this data; correct if taken) ----
    if (__builtin_expect(__any((int)sus), 0)) {
        for (int it = 0; it < NIT; ++it) {
            const u16* p = cb + (size_t)(cbase + it * BN + rB) * FEAT + q * 8;
            bf16x8 cf[4];
#pragma unroll
            for (int ks = 0; ks < 4; ++ks)
                cf[ks] = *reinterpret_cast<const bf16x8*>(p + ks * 32);
            f32x4 acc[8];
#pragma unroll
            for (int m = 0; m < 8; ++m) acc[m] = f32x4{0.f, 0.f, 0.f, 0.f};
#pragma unroll
            for (int ks = 0; ks < 4; ++ks)
#pragma unroll
                for (int m = 0; m < 8; ++m)
                    acc[m] = __builtin_amdgcn_mfma_f32_16x16x32_bf16(af[m][ks], cf[ks], acc[m], 0, 0, 0);
            const int c = cbase + it * BN + rB;
            const float ccv = cc[c], sv = scale[c];
            const int nd = node_id[c];
#pragma unroll
            for (int m = 0; m < 8; ++m) {
#pragma unroll
                for (int j = 0; j < 4; ++j) {
                    const int row = row0 + m * 16 + q * 4 + j;
                    float sqd = fmaxf(xx[row] + ccv - 2.f * acc[m][j], 0.f);
                    float tt = sqd * sv;
                    if (tt < 96.f) {
                        float phi = __expf(-tt);
                        float* orow = out + (size_t)row * OUT_TYPES;
                        const float* wc = W + nd;
                        for (int n = 0; n < OUT_TYPES; ++n)
                            atomicAdd(&orow[n], phi * wc[(size_t)n * OUT_TYPES]);
                    }
                }
            }
        }
    }
}

// ---------------- launch ------------------------------------------------------
extern "C" void kernel_launch(void* const* d_in, const int* in_sizes, int n_in,
                              void* d_out, int out_size, void* d_ws, size_t ws_size,
                              hipStream_t stream) {
    const float* x       = (const float*)d_in[0];
    const float* centres = (const float*)d_in[1];
    const float* ls      = (const float*)d_in[2];
    const int*   node_id = (const int*)d_in[3];
    const float* W       = (const float*)d_in[4];
    const float* bias    = (const float*)d_in[5];
    float* out = (float*)d_out;

    // ws: xb 1MB | cbb 4MB | cc 64KB | scale 64KB | hc 64KB | xx 16KB
    char* p = (char*)d_ws;
    u16*   xb    = (u16*)p;    p += (size_t)BATCH * FEAT * 2;
    u16*   cbb   = (u16*)p;    p += (size_t)C_TOTAL * FEAT * 2;
    float* cc    = (float*)p;  p += (size_t)C_TOTAL * 4;
    float* scale = (float*)p;  p += (size_t)C_TOTAL * 4;
    float* hc    = (float*)p;  p += (size_t)C_TOTAL * 4;
    float* xx    = (float*)p;  p += (size_t)BATCH * 4;

    hipLaunchKernelGGL(prologue_kernel, dim3(2048 + 256 + 64), dim3(256), 0, stream,
                       x, centres, ls, bias, xb, cbb, cc, scale, hc, xx, out);
    hipLaunchKernelGGL(rbf_kernel, dim3(BATCH / BM * CSPLIT), dim3(256), 0, stream,
                       xb, cbb, hc, cc, scale, node_id, xx, W, out);
}

// Round 9
// 50.522 us; speedup vs baseline: 1.2696x; 1.2696x over previous
//
#include <hip/hip_runtime.h>
#include <hip/hip_bf16.h>
#include <math.h>

#define BATCH 4096
#define FEAT 128
#define C_TOTAL 16384
#define OUT_TYPES 512

typedef short bf16x8 __attribute__((ext_vector_type(8)));
typedef float f32x4 __attribute__((ext_vector_type(4)));
typedef unsigned short u16;

typedef const __attribute__((address_space(1))) void cg_void;
typedef __attribute__((address_space(3))) void lds_void_t;

static __device__ __forceinline__ u16 f2bf(float f) {
    __hip_bfloat16 h = __float2bfloat16(f);
    return reinterpret_cast<u16&>(h);
}

// ---------------- prologue: out=bias bcast | centres prep | x prep -----------
__global__ void prologue_kernel(const float* __restrict__ x, const float* __restrict__ centres,
                                const float* __restrict__ ls, const float* __restrict__ bias,
                                u16* __restrict__ xb, u16* __restrict__ cbb,
                                float* __restrict__ cc, float* __restrict__ scale,
                                float* __restrict__ hc, float* __restrict__ xx,
                                float* __restrict__ out) {
    const int b = blockIdx.x;
    const int t = threadIdx.x;
    if (b < 2048) {                       // out[m][n] = bias[n], 8 MB
        int i = b * 256 + t;              // float4 index
        float4 bv = reinterpret_cast<const float4*>(bias)[i & 127];
        reinterpret_cast<float4*>(out)[i] = bv;
        return;
    }
    const bool is_c = (b < 2048 + 256);
    const int row = (is_c ? (b - 2048) : (b - 2304)) * 64 + (t >> 2);
    const int l4 = t & 3;
    const float* src = is_c ? centres : x;
    u16* dstb = is_c ? cbb : xb;
    const float4* p = reinterpret_cast<const float4*>(src + (size_t)row * FEAT);
    ushort4* q = reinterpret_cast<ushort4*>(dstb + (size_t)row * FEAT);
    float s = 0.f;
#pragma unroll
    for (int i = 0; i < 8; ++i) {
        float4 v = p[i * 4 + l4];
        s += v.x * v.x + v.y * v.y + v.z * v.z + v.w * v.w;
        ushort4 h;
        h.x = f2bf(v.x); h.y = f2bf(v.y); h.z = f2bf(v.z); h.w = f2bf(v.w);
        q[i * 4 + l4] = h;
    }
    s += __shfl_xor(s, 1);
    s += __shfl_xor(s, 2);
    if (l4 == 0) {
        if (is_c) {
            cc[row] = s;
            scale[row] = __expf(2.f * ls[row]);
            // exact fire condition: sqd*scale < 96 <=> d - 0.5*xx > 0.5*cc - 48/scale
            hc[row] = 0.5f * s - 48.f * __expf(-2.f * ls[row]);
        } else {
            xx[row] = s;
        }
    }
}

// ---------------- rbf: slim A-in-regs MFMA, 4 blocks/CU ----------------------
// 256 thr / 4 waves; wave-tile 64 rows x 16 cols (af[4][4]=64 VGPR, acc=16).
// All 4 waves stack on ROWS (block = 256 rows) and share one 16-centre B-tile
// per iter (broadcast LDS reads). Staging: 4 KB/iter = 1 global_load_lds(16B)
// per thread, 4 buffers, STAGE(it+2) then counted vmcnt(2) -> 2-iter lead.
// ~110 VGPR + 16 KB LDS -> 4 blocks/CU -> 4 waves/SIMD from INDEPENDENT
// blocks (independent barriers = real latency hiding).
// Screen: acc init = -0.5*min(xx) over lane rows; one 16-max tree vs hmin.
// Rare hits -> cold post-loop exact recheck + phi rank-1 atomic update.
#define BMB 256                   /* rows per block */
#define WM 64                     /* rows per wave */
#define BN 16                     /* centres per iter */
#define CSPLIT 64
#define CCHUNK (C_TOTAL / CSPLIT) /* 256 */
#define NIT (CCHUNK / BN)         /* 16 */

__global__ __launch_bounds__(256, 4)
void rbf_kernel(const u16* __restrict__ xb, const u16* __restrict__ cb,
                const float* __restrict__ hc, const float* __restrict__ cc,
                const float* __restrict__ scale, const int* __restrict__ node_id,
                const float* __restrict__ xx, const float* __restrict__ W,
                float* __restrict__ out) {
    __shared__ u16 cs[4][BN * FEAT];      // 4 x 4 KB, granule-swizzled

    const int t = threadIdx.x;
    const int lane = t & 63;
    const int w = t >> 6;                 // wave 0..3 -> row-group
    const int q = lane >> 4;              // 0..3
    const int r = lane & 15;
    // bijective XCD remap: 1024 blocks = 8 XCD x 128; per XCD: all 16 row-blocks
    // x 8 centre-chunks (~1.5 MB L2 footprint)
    const int bid = blockIdx.x;
    const int nid = (bid & 7) * 128 + (bid >> 3);
    const int row0 = (nid & 15) * BMB + w * WM;
    const int cbase = (nid >> 4) * CCHUNK;
    const int swz = r & 7;

    // ---- setup: all global metadata consumed before staging ----
    bf16x8 af[4][4];
#pragma unroll
    for (int m = 0; m < 4; ++m) {
        const u16* xrow = xb + (size_t)(row0 + m * 16 + r) * FEAT + q * 8;
#pragma unroll
        for (int ks = 0; ks < 4; ++ks)
            af[m][ks] = *reinterpret_cast<const bf16x8*>(xrow + ks * 32);
    }
    float xmin = 1e30f;                   // min xx over the 16 rows lane owns
#pragma unroll
    for (int m = 0; m < 4; ++m) {
        float4 v = *reinterpret_cast<const float4*>(&xx[row0 + m * 16 + q * 4]);
        xmin = fminf(xmin, fminf(fminf(v.x, v.y), fminf(v.z, v.w)));
    }
    const float nxh = -0.5f * xmin;
    float hmin = 1e30f;                   // min hc over lane's NIT centres
#pragma unroll
    for (int it = 0; it < NIT; ++it)
        hmin = fminf(hmin, hc[cbase + it * BN + r]);

    // ---- staging: 4 KB tile, 1 load/thread (linear LDS dest, swz source) ----
#define STAGE(IT, BUF)                                                         \
    {                                                                          \
        int rr = t >> 4;                                                       \
        int gsrc = (t & 15) ^ (rr & 7);                                        \
        __builtin_amdgcn_global_load_lds(                                      \
            (cg_void*)(cb + (size_t)(cbase + (IT) * BN + rr) * FEAT + gsrc * 8), \
            (lds_void_t*)((char*)cs[BUF] + t * 16), 16, 0, 0);                 \
    }
    STAGE(0, 0)
    STAGE(1, 1)

    unsigned sus = 0;
#pragma unroll
    for (int it = 0; it < NIT; ++it) {
        if (it + 2 < NIT) STAGE(it + 2, (it + 2) & 3)
        // wait own tile-it load only (newer stages stay in flight)
        if (it + 2 < NIT)      asm volatile("s_waitcnt vmcnt(2)" ::: "memory");
        else if (it + 1 < NIT) asm volatile("s_waitcnt vmcnt(1)" ::: "memory");
        else                   asm volatile("s_waitcnt vmcnt(0)" ::: "memory");
        __builtin_amdgcn_s_barrier();     // all waves' quarter-tiles landed
        __builtin_amdgcn_sched_barrier(0);

        const u16* brow = cs[it & 3] + r * FEAT;
        f32x4 acc[4];
#pragma unroll
        for (int m = 0; m < 4; ++m)
            acc[m] = f32x4{nxh, nxh, nxh, nxh};
        __builtin_amdgcn_s_setprio(1);
#pragma unroll
        for (int ks = 0; ks < 4; ++ks) {
            int gk = (ks * 4 + q) ^ swz;
            bf16x8 bf = *reinterpret_cast<const bf16x8*>(brow + gk * 8);
#pragma unroll
            for (int m = 0; m < 4; ++m)
                acc[m] = __builtin_amdgcn_mfma_f32_16x16x32_bf16(af[m][ks], bf, acc[m], 0, 0, 0);
        }
        __builtin_amdgcn_s_setprio(0);

        // screen: 16-wide max tree vs per-lane hmin
        float p0 = fmaxf(fmaxf(acc[0][0], acc[0][1]), fmaxf(acc[0][2], acc[0][3]));
        float p1 = fmaxf(fmaxf(acc[1][0], acc[1][1]), fmaxf(acc[1][2], acc[1][3]));
        float p2 = fmaxf(fmaxf(acc[2][0], acc[2][1]), fmaxf(acc[2][2], acc[2][3]));
        float p3 = fmaxf(fmaxf(acc[3][0], acc[3][1]), fmaxf(acc[3][2], acc[3][3]));
        sus |= (fmaxf(fmaxf(p0, p1), fmaxf(p2, p3)) > hmin) ? 1u : 0u;
    }
#undef STAGE

    // ---- cold exact path (never taken on this data; correct if taken) ----
    if (__builtin_expect(__any((int)sus), 0)) {
        for (int it = 0; it < NIT; ++it) {
            const u16* p = cb + (size_t)(cbase + it * BN + r) * FEAT + q * 8;
            bf16x8 cf[4];
#pragma unroll
            for (int ks = 0; ks < 4; ++ks)
                cf[ks] = *reinterpret_cast<const bf16x8*>(p + ks * 32);
            f32x4 acc[4];
#pragma unroll
            for (int m = 0; m < 4; ++m) acc[m] = f32x4{0.f, 0.f, 0.f, 0.f};
#pragma unroll
            for (int ks = 0; ks < 4; ++ks)
#pragma unroll
                for (int m = 0; m < 4; ++m)
                    acc[m] = __builtin_amdgcn_mfma_f32_16x16x32_bf16(af[m][ks], cf[ks], acc[m], 0, 0, 0);
            const int c = cbase + it * BN + r;
            const float ccv = cc[c], sv = scale[c];
            const int nd = node_id[c];
#pragma unroll
            for (int m = 0; m < 4; ++m) {
#pragma unroll
                for (int j = 0; j < 4; ++j) {
                    const int row = row0 + m * 16 + q * 4 + j;
                    float sqd = fmaxf(xx[row] + ccv - 2.f * acc[m][j], 0.f);
                    float tt = sqd * sv;
                    if (tt < 96.f) {
                        float phi = __expf(-tt);
                        float* orow = out + (size_t)row * OUT_TYPES;
                        const float* wc = W + nd;
                        for (int n = 0; n < OUT_TYPES; ++n)
                            atomicAdd(&orow[n], phi * wc[(size_t)n * OUT_TYPES]);
                    }
                }
            }
        }
    }
}

// ---------------- launch ------------------------------------------------------
extern "C" void kernel_launch(void* const* d_in, const int* in_sizes, int n_in,
                              void* d_out, int out_size, void* d_ws, size_t ws_size,
                              hipStream_t stream) {
    const float* x       = (const float*)d_in[0];
    const float* centres = (const float*)d_in[1];
    const float* ls      = (const float*)d_in[2];
    const int*   node_id = (const int*)d_in[3];
    const float* W       = (const float*)d_in[4];
    const float* bias    = (const float*)d_in[5];
    float* out = (float*)d_out;

    // ws: xb 1MB | cbb 4MB | cc 64KB | scale 64KB | hc 64KB | xx 16KB
    char* p = (char*)d_ws;
    u16*   xb    = (u16*)p;    p += (size_t)BATCH * FEAT * 2;
    u16*   cbb   = (u16*)p;    p += (size_t)C_TOTAL * FEAT * 2;
    float* cc    = (float*)p;  p += (size_t)C_TOTAL * 4;
    float* scale = (float*)p;  p += (size_t)C_TOTAL * 4;
    float* hc    = (float*)p;  p += (size_t)C_TOTAL * 4;
    float* xx    = (float*)p;  p += (size_t)BATCH * 4;

    hipLaunchKernelGGL(prologue_kernel, dim3(2048 + 256 + 64), dim3(256), 0, stream,
                       x, centres, ls, bias, xb, cbb, cc, scale, hc, xx, out);
    hipLaunchKernelGGL(rbf_kernel, dim3((BATCH / BMB) * CSPLIT), dim3(256), 0, stream,
                       xb, cbb, hc, cc, scale, node_id, xx, W, out);
}